// Round 3
// baseline (333.834 us; speedup 1.0000x reference)
//
#include <hip/hip_runtime.h>
#include <math.h>

// NoisyTopkRouter: B=8,T=4096,NE=1024,E=16,TOPK=2,LIN=1824
// tokens = 32768; streamed features = 1792 (city-32 folded into a constant)
// out = [router 32768*16][indices 32768*2][gate1 32768*16] all f32
//
// R7: R4 dataflow (optimal fmac/ds_read=16 at Tl=El=8-ish) with the two
// measured defects fixed:
//  (a) R4 was 2 waves/SIMD (88KB LDS) -> latency-bound. Now ONE 1024-thr
//      block/CU, 16 waves = 4/SIMD, LDS 68KB (A dbuf only).
//  (b) R4's W-from-LDS was half the LDS issue (41us floor > 24us VALU).
//      R6's W-from-SGPR needs 256 scalars/chunk > ~102 budget (serialized
//      s_load stalls: VALUBusy 19.5%). Now W -> VGPRs from GLOBAL (L1/L2
//      hot, 8KB/chunk/CU, broadcast addrs); LDS carries A only.
// Per lane/chunk: 8 ds_read_b128 (A) + 16 global dwordx4 (W) + 256 fmac.
// Per-CU/chunk: VALU 2240cy > LDS 1920cy > VMEM ~1.1Kcy -> VALU-bound.
// Wave = (token-half h, k-slab s); lane = 4tok x 8e; acc 32 VGPR.

#define TOKS 128
#define NCHUNK 28
#define I_OFF 524288        // 32768*16
#define G_OFF 589824        // 524288 + 32768*2
#define SA 68               // pad 64->68: A-read 2-way banks (free, m136)
#define SP 36               // score rows: f4-aligned, reduction is tiny

__device__ __forceinline__ float softplus_f(float x) {
  // jax.nn.softplus = max(x,0) + log1p(exp(-|x|))
  return fmaxf(x, 0.0f) + log1pf(expf(-fabsf(x)));
}

__global__ __launch_bounds__(1024, 1) void router_kernel(
    const float* __restrict__ mh, const float* __restrict__ dt,
    const float* __restrict__ dd, const float* __restrict__ rg,
    const float* __restrict__ de, const float* __restrict__ cemb_all,
    const float* __restrict__ w_route, const float* __restrict__ b_route,
    const float* __restrict__ w_noise, const float* __restrict__ b_noise,
    const float* __restrict__ eps, const int* __restrict__ city_index,
    float* __restrict__ out) {
  // A dbuf 2*128*68 = 17408 f; reduction overlay 2*64*36 = 4608 f (in sA0)
  __shared__ float smem[17408];
  __shared__ float city_l[32];
  float* sA0 = smem;
  float* sA1 = smem + 8704;

  const int tid = threadIdx.x;
  const int w   = tid >> 6;
  const int ln  = tid & 63;
  const int h   = w >> 3;          // token half 0/1 (64 tokens each)
  const int s   = w & 7;           // k-slab: k = s*8 .. s*8+7 of chunk
  const int tg  = ln & 15;         // token group: rows tg+16j, j=0..3
  const int eg  = ln >> 4;         // 0..3 -> e-cols eg*8..eg*8+7 (of 32)
  const int blockTok = blockIdx.x * TOKS;

  // ---- constant: bias + city_embed . W[1024:1056] ----
  if (tid < 32) {
    const int e = tid & 15;
    const float* wsrc = (tid < 16) ? w_route : w_noise;
    const float* bsrc = (tid < 16) ? b_route : b_noise;
    const float* ce = cemb_all + city_index[0] * 32;
    float sacc = bsrc[e];
#pragma unroll
    for (int j = 0; j < 32; ++j)
      sacc = fmaf(ce[j], wsrc[(1024 + j) * 16 + e], sacc);
    city_l[tid] = sacc;
  }

  float4 accL[4], accH[4];
#pragma unroll
  for (int j = 0; j < 4; ++j) {
    accL[j] = make_float4(0.f, 0.f, 0.f, 0.f);
    accH[j] = make_float4(0.f, 0.f, 0.f, 0.f);
  }

  // A staging: chunk = 128 tok x 64 k = 2048 f4 / 1024 thr = 2 f4 each.
  const int arow = tid >> 4;           // 0..63; rows arow and arow+64
  const int acol = (tid & 15) * 4;

  float4 AR0, AR1;  // named regs: no scratch

  auto a_src = [&](int g, int row) -> const float* {
    const float* base; int stride;
    if (g < 16)      { base = mh + g * 64;        stride = 1024; }
    else if (g < 20) { base = dt + (g - 16) * 64; stride = 256; }
    else if (g < 24) { base = dd + (g - 20) * 64; stride = 256; }
    else             { base = (g < 26) ? rg + (g - 24) * 64
                                       : de + (g - 26) * 64;
                       stride = 128; }
    return base + (size_t)(blockTok + row) * stride;
  };

  auto prefetch = [&](int g) {
    AR0 = *(const float4*)(a_src(g, arow +  0) + acol);
    AR1 = *(const float4*)(a_src(g, arow + 64) + acol);
  };

  auto stage = [&](float* A) {
    *(float4*)&A[(arow +  0) * SA + acol] = AR0;
    *(float4*)&A[(arow + 64) * SA + acol] = AR1;
  };

  prefetch(0);
  stage(sA0);
  __syncthreads();

  // lane-fixed addressing
  const int abase = (h * 64 + tg) * SA + s * 8;          // A read base
  const float* wsel = (eg < 2) ? w_route : w_noise;      // route|noise half
  const int ec = (eg & 1) * 8;                           // col 0 or 8 (of 16)

  for (int c = 0; c < NCHUNK; ++c) {
    const float* A = (c & 1) ? sA1 : sA0;

    if (c + 1 < NCHUNK) prefetch(c + 1);  // global loads fly over compute

    const int kb = c * 64 + ((c >= 16) ? 32 : 0);  // skip city rows
    const float* wb = wsel + (size_t)(kb + s * 8) * 16 + ec;

    // this lane's 4 tokens x 8 k (1 b128 pair per token)
    float4 aL[4], aH[4];
#pragma unroll
    for (int j = 0; j < 4; ++j) {
      aL[j] = *(const float4*)&A[abase + j * (16 * SA)];
      aH[j] = *(const float4*)&A[abase + j * (16 * SA) + 4];
    }

#pragma unroll
    for (int k = 0; k < 8; ++k) {
      const float4 w0 = *(const float4*)(wb + k * 16);      // cols ec..ec+3
      const float4 w1 = *(const float4*)(wb + k * 16 + 4);  // cols ec+4..+7
#pragma unroll
      for (int j = 0; j < 4; ++j) {
        const float ak =
            (k == 0) ? aL[j].x : (k == 1) ? aL[j].y : (k == 2) ? aL[j].z
          : (k == 3) ? aL[j].w : (k == 4) ? aH[j].x : (k == 5) ? aH[j].y
          : (k == 6) ? aH[j].z : aH[j].w;
        accL[j].x = fmaf(ak, w0.x, accL[j].x);
        accL[j].y = fmaf(ak, w0.y, accL[j].y);
        accL[j].z = fmaf(ak, w0.z, accL[j].z);
        accL[j].w = fmaf(ak, w0.w, accL[j].w);
        accH[j].x = fmaf(ak, w1.x, accH[j].x);
        accH[j].y = fmaf(ak, w1.y, accH[j].y);
        accH[j].z = fmaf(ak, w1.z, accH[j].z);
        accH[j].w = fmaf(ak, w1.w, accH[j].w);
      }
    }

    if (c + 1 < NCHUNK) stage((c & 1) ? sA0 : sA1);
    __syncthreads();  // next buffer visible; all waves done with current
  }

  // ---- split-K reduction: 8 serial-RMW rounds, both halves in parallel ----
  // sS[h][64][SP] overlays sA0 (last chunk c=27 computed from sA1: safe).
  for (int r = 0; r < 8; ++r) {
    if (s == r) {
      float* Sb = &smem[h * (64 * SP)];
#pragma unroll
      for (int j = 0; j < 4; ++j) {
        float* p = &Sb[(tg + 16 * j) * SP + eg * 8];
        if (r == 0) {
          *(float4*)(p)     = accL[j];
          *(float4*)(p + 4) = accH[j];
        } else {
          float4 x0 = *(float4*)(p), x1 = *(float4*)(p + 4);
          x0.x += accL[j].x; x0.y += accL[j].y; x0.z += accL[j].z; x0.w += accL[j].w;
          x1.x += accH[j].x; x1.y += accH[j].y; x1.z += accH[j].z; x1.w += accH[j].w;
          *(float4*)(p)     = x0;
          *(float4*)(p + 4) = x1;
        }
      }
    }
    __syncthreads();
  }

  // ---- epilogue: one lane per token (tid 0..127) ----
  if (tid < TOKS) {
    const int tokg = blockTok + tid;           // tid = h*64 + t_local
    const float* Sb = &smem[(tid >> 6) * (64 * SP) + (tid & 63) * SP];
    float l[32];
#pragma unroll
    for (int e4 = 0; e4 < 8; ++e4) {
      float4 s0 = *(const float4*)&Sb[e4 * 4];
      l[e4 * 4 + 0] = s0.x; l[e4 * 4 + 1] = s0.y;
      l[e4 * 4 + 2] = s0.z; l[e4 * 4 + 3] = s0.w;
    }
#pragma unroll
    for (int e = 0; e < 32; ++e) l[e] += city_l[e];

    const float* ep = eps + (size_t)tokg * 16;
    float n[16];
#pragma unroll
    for (int e = 0; e < 16; ++e)
      n[e] = fmaf(ep[e], softplus_f(l[16 + e]), l[e]);

    // top-2, lowest-index tie-break (matches lax.top_k)
    float m1 = -INFINITY; int i1 = 0;
#pragma unroll
    for (int e = 0; e < 16; ++e)
      if (n[e] > m1) { m1 = n[e]; i1 = e; }
    float m2 = -INFINITY; int i2 = 0;
#pragma unroll
    for (int e = 0; e < 16; ++e)
      if (e != i1 && n[e] > m2) { m2 = n[e]; i2 = e; }

    float ex[16], Z = 0.f;
#pragma unroll
    for (int e = 0; e < 16; ++e) { ex[e] = expf(n[e] - m1); Z += ex[e]; }
    const float invZ  = 1.0f / Z;
    const float invZ2 = 1.0f / (1.0f + expf(m2 - m1));  // ex[i1]=1

    float r[16], g1[16];
#pragma unroll
    for (int e = 0; e < 16; ++e) {
      r[e]  = (e == i1 || e == i2) ? ex[e] * invZ2 : 0.0f;
      g1[e] = ex[e] * invZ;
    }

    float* ro = out + (size_t)tokg * 16;
#pragma unroll
    for (int e4 = 0; e4 < 4; ++e4)
      *(float4*)(ro + e4 * 4) = make_float4(r[e4*4], r[e4*4+1], r[e4*4+2], r[e4*4+3]);

    out[I_OFF + (size_t)tokg * 2 + 0] = (float)i1;
    out[I_OFF + (size_t)tokg * 2 + 1] = (float)i2;

    float* go = out + G_OFF + (size_t)tokg * 16;
#pragma unroll
    for (int e4 = 0; e4 < 4; ++e4)
      *(float4*)(go + e4 * 4) = make_float4(g1[e4*4], g1[e4*4+1], g1[e4*4+2], g1[e4*4+3]);
  }
}

extern "C" void kernel_launch(void* const* d_in, const int* in_sizes, int n_in,
                              void* d_out, int out_size, void* d_ws, size_t ws_size,
                              hipStream_t stream) {
  const float* mh = (const float*)d_in[0];   // [8,4096,1024]
  const float* dt = (const float*)d_in[1];   // [8,4096,256]
  const float* dd = (const float*)d_in[2];   // [8,4096,256]
  const float* rg = (const float*)d_in[3];   // [8,4096,128]
  const float* de = (const float*)d_in[4];   // [8,4096,128]
  const float* ce = (const float*)d_in[5];   // [4,32]
  const float* wr = (const float*)d_in[6];   // [1824,16]
  const float* br = (const float*)d_in[7];   // [16]
  const float* wn = (const float*)d_in[8];   // [1824,16]
  const float* bn = (const float*)d_in[9];   // [16]
  const float* ep = (const float*)d_in[10];  // [8,4096,16]
  const int*   ci = (const int*)d_in[11];    // scalar
  float* out = (float*)d_out;

  router_kernel<<<256, 1024, 0, stream>>>(mh, dt, dd, rg, de, ce, wr, br, wn, bn,
                                          ep, ci, out);
}

// Round 5
// 295.000 us; speedup vs baseline: 1.1316x; 1.1316x over previous
//
#include <hip/hip_runtime.h>
#include <math.h>

// NoisyTopkRouter: B=8,T=4096,NE=1024,E=16,TOPK=2,LIN=1824
// tokens = 32768; streamed features = 1792 (city-32 folded into a constant)
// out = [router 32768*16][indices 32768*2][gate1 32768*16] all f32
//
// R9: R8 with two fixes.
//  BUG (R8 fail): sW1 was sW0+1024 floats but a W chunk is 64x32 = 2048
//    floats -> W double-buffers overlapped; chunk c+1 staging clobbered
//    rows 32..63 of chunk c's W. Fixed offsets.
//  LDS budget: runtime adds +384B to every LDS alloc (R4/R7 counters), so
//    R8's exact-80KB = 82304B -> 1 block/CU. Re-plan: TOKS=64, 512 thr,
//    grid 512; LDS = A dbuf 2*64*64 + W dbuf 2*64*32 = 49152B (+384) ->
//    2 blocks/CU = 16 waves/CU = 4/SIMD, two barrier domains per CU.
// Structure (unchanged from R8): global_load_lds DMA staging, LINEAR LDS
// dest + XOR-swizzled GLOBAL source + same-XOR read (rule #21), one
// barrier per chunk with explicit vmcnt(0) drain (T3 minimal recipe).
// Lane tile 4tok x 8e, 8-wave split-K: 256 fmac / 16 b128 = ratio 16.

#define TOKS 64
#define NCHUNK 28
#define I_OFF 524288        // 32768*16
#define G_OFF 589824        // 524288 + 32768*2
#define SS 36               // score-row stride (reduction scratch)

__device__ __forceinline__ float softplus_f(float x) {
  // jax.nn.softplus = max(x,0) + log1p(exp(-|x|))
  return fmaxf(x, 0.0f) + log1pf(expf(-fabsf(x)));
}

__device__ __forceinline__ float get_comp(const float4& v, int kk) {
  return kk == 0 ? v.x : kk == 1 ? v.y : kk == 2 ? v.z : v.w;
}

__device__ __forceinline__ void dma16(const float* g, float* l) {
  __builtin_amdgcn_global_load_lds(
      (const __attribute__((address_space(1))) void*)g,
      (__attribute__((address_space(3))) void*)l, 16, 0, 0);
}

__global__ __launch_bounds__(512, 2) void router_kernel(
    const float* __restrict__ mh, const float* __restrict__ dt,
    const float* __restrict__ dd, const float* __restrict__ rg,
    const float* __restrict__ de, const float* __restrict__ cemb_all,
    const float* __restrict__ w_route, const float* __restrict__ b_route,
    const float* __restrict__ w_noise, const float* __restrict__ b_noise,
    const float* __restrict__ eps, const int* __restrict__ city_index,
    float* __restrict__ out) {
  // [0,4096) A0 | [4096,8192) A1 | [8192,10240) W0 | [10240,12288) W1
  // post-loop overlay in dead A0: sS [64][36] = [0,2304), city [2304,2336)
  __shared__ float smem[12288];   // 49152 B (+384 runtime) -> 2 blocks/CU
  float* sA0 = smem;
  float* sA1 = smem + 4096;
  float* sW0 = smem + 8192;
  float* sW1 = smem + 10240;      // W chunk = 64*32 = 2048 floats (R8 bug)
  float* sS  = smem;
  float* cityL = smem + 2304;

  const int tid = threadIdx.x;
  const int w   = tid >> 6;        // wave 0..7: k-slab [w*8, w*8+8) of chunk
  const int ln  = tid & 63;
  const int tg  = ln & 15;         // tokens {tg + 16j}, j=0..3
  const int eg  = ln >> 4;         // e-cols eg*8..eg*8+7 (of 32 = route|noise)
  const int blockTok = blockIdx.x * TOKS;

  float4 accL[4], accH[4];
#pragma unroll
  for (int j = 0; j < 4; ++j) {
    accL[j] = make_float4(0.f, 0.f, 0.f, 0.f);
    accH[j] = make_float4(0.f, 0.f, 0.f, 0.f);
  }

  auto a_src = [&](int g, int row) -> const float* {
    const float* base; int stride;
    if (g < 16)      { base = mh + g * 64;        stride = 1024; }
    else if (g < 20) { base = dt + (g - 16) * 64; stride = 256; }
    else if (g < 24) { base = dd + (g - 20) * 64; stride = 256; }
    else             { base = (g < 26) ? rg + (g - 24) * 64
                                       : de + (g - 26) * 64;
                       stride = 128; }
    return base + (size_t)(blockTok + row) * stride;
  };

  // DMA one chunk: A 1024 f4 slots (2/thread), W 512 f4 slots (1/thread).
  // LDS dest LINEAR slot*16B (wave-uniform base + lane*16 per instr); A
  // source column pre-swizzled: LDS slot (r, p) holds global f4-col
  // p ^ (r&15)  (stays inside the row's 256B segment -> coalesced).
  auto stageDMA = [&](int g, float* Abuf, float* Wbuf) {
#pragma unroll
    for (int i = 0; i < 2; ++i) {
      const int slot = i * 512 + tid;
      const int r    = slot >> 4;                 // token row 0..63
      const int c4   = (slot & 15) ^ (r & 15);    // swizzled source col
      dma16(a_src(g, r) + c4 * 4, Abuf + slot * 4);
    }
    {
      const int r  = tid >> 3;               // k-row 0..63
      const int c4 = tid & 7;                // 8 f4 per row (32 e)
      const int kb = g * 64 + ((g >= 16) ? 32 : 0) + r;  // skip city rows
      const float* ws = (c4 < 4) ? (w_route + kb * 16 + c4 * 4)
                                 : (w_noise + kb * 16 + (c4 - 4) * 4);
      dma16(ws, Wbuf + tid * 4);
    }
  };

  stageDMA(0, sA0, sW0);
  asm volatile("s_waitcnt vmcnt(0)" ::: "memory");
  __syncthreads();   // chunk 0 resident

  // lane-fixed read addressing (swizzled A columns, j-independent)
  const int c4x0 = (((w << 1) | 0) ^ tg) << 2;   // float offset of f4 slot
  const int c4x1 = (((w << 1) | 1) ^ tg) << 2;
  const int k0 = w * 8;

  for (int c = 0; c < NCHUNK; ++c) {
    const float* A = (c & 1) ? sA1 : sA0;
    const float* W = (c & 1) ? sW1 : sW0;

    if (c + 1 < NCHUNK)
      stageDMA(c + 1, (c & 1) ? sA0 : sA1, (c & 1) ? sW0 : sW1);

#pragma unroll
    for (int q = 0; q < 2; ++q) {
      const int cofs = q ? c4x1 : c4x0;
      float4 a[4];
#pragma unroll
      for (int j = 0; j < 4; ++j)
        a[j] = *(const float4*)&A[(tg + 16 * j) * 64 + cofs];  // 2-way: free
#pragma unroll
      for (int kk = 0; kk < 4; ++kk) {
        const int krow = k0 + q * 4 + kk;
        float4 wv0 = *(const float4*)&W[krow * 32 + eg * 8];      // bcast
        float4 wv1 = *(const float4*)&W[krow * 32 + eg * 8 + 4];  // bcast
#pragma unroll
        for (int j = 0; j < 4; ++j) {
          const float s = get_comp(a[j], kk);
          accL[j].x = fmaf(s, wv0.x, accL[j].x);
          accL[j].y = fmaf(s, wv0.y, accL[j].y);
          accL[j].z = fmaf(s, wv0.z, accL[j].z);
          accL[j].w = fmaf(s, wv0.w, accL[j].w);
          accH[j].x = fmaf(s, wv1.x, accH[j].x);
          accH[j].y = fmaf(s, wv1.y, accH[j].y);
          accH[j].z = fmaf(s, wv1.z, accH[j].z);
          accH[j].w = fmaf(s, wv1.w, accH[j].w);
        }
      }
    }

    asm volatile("s_waitcnt vmcnt(0)" ::: "memory");  // next chunk's DMA done
    __syncthreads();   // all reads of current buffer done
  }

  // ---- city constants into dead A0 region (consumed by epilogue) ----
  if (tid < 32) {
    const int e = tid & 15;
    const float* wsrc = (tid < 16) ? w_route : w_noise;
    const float* bsrc = (tid < 16) ? b_route : b_noise;
    const float* ce = cemb_all + city_index[0] * 32;
    float sacc = bsrc[e];
#pragma unroll
    for (int j = 0; j < 32; ++j)
      sacc = fmaf(ce[j], wsrc[(1024 + j) * 16 + e], sacc);
    cityL[tid] = sacc;
  }

  // ---- 8-way split-K reduction: serial RMW rounds into sS[64][36] ----
  // (sS overlays A0; last chunk c=27 computed from A1/W1: safe)
  for (int r = 0; r < 8; ++r) {
    if (w == r) {
#pragma unroll
      for (int j = 0; j < 4; ++j) {
        float* p = &sS[(tg + 16 * j) * SS + eg * 8];
        if (r == 0) {
          *(float4*)(p)     = accL[j];
          *(float4*)(p + 4) = accH[j];
        } else {
          float4 x0 = *(float4*)(p), x1 = *(float4*)(p + 4);
          x0.x += accL[j].x; x0.y += accL[j].y; x0.z += accL[j].z; x0.w += accL[j].w;
          x1.x += accH[j].x; x1.y += accH[j].y; x1.z += accH[j].z; x1.w += accH[j].w;
          *(float4*)(p)     = x0;
          *(float4*)(p + 4) = x1;
        }
      }
    }
    __syncthreads();
  }

  // ---- epilogue: one lane per token ----
  if (tid < TOKS) {
    const int tokg = blockTok + tid;
    float l[32];
#pragma unroll
    for (int e4 = 0; e4 < 8; ++e4) {
      float4 s0 = *(const float4*)&sS[tid * SS + e4 * 4];
      l[e4 * 4 + 0] = s0.x; l[e4 * 4 + 1] = s0.y;
      l[e4 * 4 + 2] = s0.z; l[e4 * 4 + 3] = s0.w;
    }
#pragma unroll
    for (int e = 0; e < 32; ++e) l[e] += cityL[e];

    const float* ep = eps + (size_t)tokg * 16;
    float n[16];
#pragma unroll
    for (int e = 0; e < 16; ++e)
      n[e] = fmaf(ep[e], softplus_f(l[16 + e]), l[e]);

    // top-2, lowest-index tie-break (matches lax.top_k)
    float m1 = -INFINITY; int i1 = 0;
#pragma unroll
    for (int e = 0; e < 16; ++e)
      if (n[e] > m1) { m1 = n[e]; i1 = e; }
    float m2 = -INFINITY; int i2 = 0;
#pragma unroll
    for (int e = 0; e < 16; ++e)
      if (e != i1 && n[e] > m2) { m2 = n[e]; i2 = e; }

    float ex[16], Z = 0.f;
#pragma unroll
    for (int e = 0; e < 16; ++e) { ex[e] = expf(n[e] - m1); Z += ex[e]; }
    const float invZ  = 1.0f / Z;
    const float invZ2 = 1.0f / (1.0f + expf(m2 - m1));  // ex[i1]=1

    float r[16], g1[16];
#pragma unroll
    for (int e = 0; e < 16; ++e) {
      r[e]  = (e == i1 || e == i2) ? ex[e] * invZ2 : 0.0f;
      g1[e] = ex[e] * invZ;
    }

    float* ro = out + (size_t)tokg * 16;
#pragma unroll
    for (int e4 = 0; e4 < 4; ++e4)
      *(float4*)(ro + e4 * 4) = make_float4(r[e4*4], r[e4*4+1], r[e4*4+2], r[e4*4+3]);

    out[I_OFF + (size_t)tokg * 2 + 0] = (float)i1;
    out[I_OFF + (size_t)tokg * 2 + 1] = (float)i2;

    float* go = out + G_OFF + (size_t)tokg * 16;
#pragma unroll
    for (int e4 = 0; e4 < 4; ++e4)
      *(float4*)(go + e4 * 4) = make_float4(g1[e4*4], g1[e4*4+1], g1[e4*4+2], g1[e4*4+3]);
  }
}

extern "C" void kernel_launch(void* const* d_in, const int* in_sizes, int n_in,
                              void* d_out, int out_size, void* d_ws, size_t ws_size,
                              hipStream_t stream) {
  const float* mh = (const float*)d_in[0];   // [8,4096,1024]
  const float* dt = (const float*)d_in[1];   // [8,4096,256]
  const float* dd = (const float*)d_in[2];   // [8,4096,256]
  const float* rg = (const float*)d_in[3];   // [8,4096,128]
  const float* de = (const float*)d_in[4];   // [8,4096,128]
  const float* ce = (const float*)d_in[5];   // [4,32]
  const float* wr = (const float*)d_in[6];   // [1824,16]
  const float* br = (const float*)d_in[7];   // [16]
  const float* wn = (const float*)d_in[8];   // [1824,16]
  const float* bn = (const float*)d_in[9];   // [16]
  const float* ep = (const float*)d_in[10];  // [8,4096,16]
  const int*   ci = (const int*)d_in[11];    // scalar
  float* out = (float*)d_out;

  router_kernel<<<512, 512, 0, stream>>>(mh, dt, dd, rg, de, ce, wr, br, wn, bn,
                                         ep, ci, out);
}